// Round 1
// baseline (1322.081 us; speedup 1.0000x reference)
//
#include <hip/hip_runtime.h>
#include <hip/hip_bf16.h>
#include <stdint.h>

using f16 = _Float16;
typedef _Float16 f16x8 __attribute__((ext_vector_type(8)));
typedef float f32x4 __attribute__((ext_vector_type(4)));

static constexpr int HW = 4096;        // H*W
static constexpr int CC = 256;         // channels
static constexpr int ROWS = 131072;    // B*H*W
static constexpr int NWIN = 2048;      // B * windows-per-image
static constexpr int CHUNKS = 8;
static constexpr int CROWS = ROWS / CHUNKS;   // 16384 rows per chunk
static constexpr int CWINS = NWIN / CHUNKS;   // 256 windows per chunk
static constexpr int SSH = 4;          // shift

// workspace layout (bytes)
static constexpr size_t OFF_WQ   = 0;                                  // qkv_w f16  768*256
static constexpr size_t OFF_WP   = OFF_WQ + (size_t)768*256*2;         // proj_w f16 256*256
static constexpr size_t OFF_W1   = OFF_WP + (size_t)256*256*2;         // fc1_w f16  1024*256
static constexpr size_t OFF_W2   = OFF_W1 + (size_t)1024*256*2;        // fc2_w f16  256*1024
static constexpr size_t OFF_HWIN = OFF_W2 + (size_t)256*1024*2;        // 131072*256 f16 (aliased by m_in)
static constexpr size_t OFF_Q    = OFF_HWIN + (size_t)ROWS*CC*2;       // chunk 256win*8h*64*32 f16
static constexpr size_t OFF_K    = OFF_Q + (size_t)CWINS*8*64*32*2;
static constexpr size_t OFF_V    = OFF_K + (size_t)CWINS*8*64*32*2;
static constexpr size_t OFF_AW   = OFF_V + (size_t)CWINS*8*64*32*2;    // chunk 16384*256 f16
static constexpr size_t OFF_MH   = OFF_AW + (size_t)CROWS*CC*2;        // chunk 16384*1024 f16
// total ~136 MB

__global__ void k_cvt(const float* __restrict__ s, f16* __restrict__ d, int n) {
    int i = blockIdx.x * 256 + threadIdx.x;
    if (i < n) d[i] = (f16)s[i];
}

// LayerNorm over C=256; WIN=true maps dest (windowed, rolled) row -> source row in x.
template<bool WIN>
__global__ __launch_bounds__(256) void k_ln(const float* __restrict__ x,
                                            const float* __restrict__ g,
                                            const float* __restrict__ be,
                                            f16* __restrict__ dst) {
    int row = blockIdx.x * 4 + (threadIdx.x >> 6);
    int lane = threadIdx.x & 63;
    size_t srow;
    if constexpr (WIN) {
        int n = row & 63, win = (row >> 6) & 63, b = row >> 12;
        int hh  = ((win >> 3) << 3) | (n >> 3);
        int wwc = ((win & 7) << 3) | (n & 7);
        int ho = (hh + SSH) & 63, wo = (wwc + SSH) & 63;   // rolled[hh] = x[(hh+SS)%64]
        srow = (size_t)b * HW + ho * 64 + wo;
    } else {
        srow = (size_t)row;
    }
    float4 v = ((const float4*)(x + srow * CC))[lane];
    float s  = v.x + v.y + v.z + v.w;
    float s2 = v.x*v.x + v.y*v.y + v.z*v.z + v.w*v.w;
#pragma unroll
    for (int off = 32; off; off >>= 1) { s += __shfl_xor(s, off); s2 += __shfl_xor(s2, off); }
    float mean = s * (1.f/256.f);
    float rstd = rsqrtf(s2 * (1.f/256.f) - mean*mean + 1e-5f);
    float4 gv = ((const float4*)g)[lane];
    float4 bv = ((const float4*)be)[lane];
    f16 ob[4];
    ob[0] = (f16)((v.x-mean)*rstd*gv.x + bv.x);
    ob[1] = (f16)((v.y-mean)*rstd*gv.y + bv.y);
    ob[2] = (f16)((v.z-mean)*rstd*gv.z + bv.z);
    ob[3] = (f16)((v.w-mean)*rstd*gv.w + bv.w);
    *(uint2*)(dst + (size_t)row * CC + lane * 4) = *(const uint2*)ob;
}

// GEMM: out[M x N] = A[M x K] * Wt[N x K]^T (+bias, epilogue EPI).
// 256 thr = 4 waves (2x2 of 64x64), tile 128x128, BK=32, mfma 16x16x32 f16.
// EPI: 0=qkv split(q-scaled), 1=proj+unshift+residual->outf, 2=fc1+gelu->outh, 3=fc2+residual(outf in-place)
template<int KDIM, int EPI>
__global__ __launch_bounds__(256) void k_gemm(const f16* __restrict__ A,
                                              const f16* __restrict__ Wt,
                                              const float* __restrict__ bias,
                                              int rowbase,
                                              const float* __restrict__ x_in,
                                              float* outf, f16* __restrict__ outh,
                                              f16* __restrict__ q, f16* __restrict__ kk,
                                              f16* __restrict__ vv) {
    __shared__ f16 As[128 * 32];
    __shared__ f16 Bs[128 * 32];
    const int tid = threadIdx.x;
    const int m0 = blockIdx.x * 128, n0 = blockIdx.y * 128;
    const int wave = tid >> 6, lane = tid & 63;
    const int wm = (wave >> 1) * 64, wn = (wave & 1) * 64;
    const int lr = lane & 15, kq = lane >> 4;
    f32x4 acc[4][4];
#pragma unroll
    for (int i = 0; i < 4; i++)
#pragma unroll
        for (int j = 0; j < 4; j++) acc[i][j] = f32x4{0.f, 0.f, 0.f, 0.f};

    for (int k0 = 0; k0 < KDIM; k0 += 32) {
#pragma unroll
        for (int t = 0; t < 2; t++) {
            int idx = tid + t * 256;          // 0..511 16B chunks
            int r = idx >> 2, c8 = idx & 3;
            *(uint4*)(&As[idx * 8]) = *(const uint4*)(&A [(size_t)(m0 + r) * KDIM + k0 + c8 * 8]);
            *(uint4*)(&Bs[idx * 8]) = *(const uint4*)(&Wt[(size_t)(n0 + r) * KDIM + k0 + c8 * 8]);
        }
        __syncthreads();
        f16x8 af[4], bfv[4];
#pragma unroll
        for (int i = 0; i < 4; i++) {
            af[i]  = *(const f16x8*)(&As[(wm + i * 16 + lr) * 32 + kq * 8]);
            bfv[i] = *(const f16x8*)(&Bs[(wn + i * 16 + lr) * 32 + kq * 8]);
        }
#pragma unroll
        for (int mi = 0; mi < 4; mi++)
#pragma unroll
            for (int ni = 0; ni < 4; ni++)
                acc[mi][ni] = __builtin_amdgcn_mfma_f32_16x16x32_f16(af[mi], bfv[ni], acc[mi][ni], 0, 0, 0);
        __syncthreads();
    }

#pragma unroll
    for (int mi = 0; mi < 4; mi++)
#pragma unroll
        for (int ni = 0; ni < 4; ni++)
#pragma unroll
            for (int j = 0; j < 4; j++) {
                int lrow = m0 + wm + mi * 16 + kq * 4 + j;   // C/D: row=(lane>>4)*4+j
                int gcol = n0 + wn + ni * 16 + lr;           //      col=lane&15
                float val = acc[mi][ni][j] + bias[gcol];
                int grow = rowbase + lrow;
                if constexpr (EPI == 0) {        // qkv: split into per-head q,k,v (chunk-local)
                    int s = gcol >> 8, h2 = (gcol >> 5) & 7, d = gcol & 31;
                    if (s == 0) val *= 0.1767766952966369f;  // HD^-0.5
                    f16* dst = (s == 0) ? q : (s == 1 ? kk : vv);
                    int winl = lrow >> 6, n = lrow & 63;
                    dst[(((size_t)winl * 8 + h2) * 64 + n) * 32 + d] = (f16)val;
                } else if constexpr (EPI == 1) { // proj + un-shift + shortcut residual -> x2 (in d_out)
                    int n = grow & 63, win = (grow >> 6) & 63, b = grow >> 12;
                    int hh  = ((win >> 3) << 3) | (n >> 3);
                    int wwc = ((win & 7) << 3) | (n & 7);
                    int ho = (hh + SSH) & 63, wo = (wwc + SSH) & 63;
                    size_t idx = ((size_t)b * HW + ho * 64 + wo) * CC + gcol;
                    outf[idx] = x_in[idx] + val;
                } else if constexpr (EPI == 2) { // fc1 + gelu(tanh approx, JAX default)
                    float z = 0.7978845608028654f * (val + 0.044715f * val * val * val);
                    float t = 1.f - 2.f / (__expf(2.f * z) + 1.f);
                    outh[(size_t)lrow * 1024 + gcol] = (f16)(0.5f * val * (1.f + t));
                } else {                          // fc2 + residual: d_out holds x2, read-modify-write
                    size_t idx = (size_t)grow * CC + gcol;
                    outf[idx] = outf[idx] + val;
                }
            }
}

// One wave per (window, head). Scores/P in LDS [key][query-lane]; K,V staged f32.
__global__ __launch_bounds__(64) void k_attn(const f16* __restrict__ q,
                                             const f16* __restrict__ kk,
                                             const f16* __restrict__ vv,
                                             const float* __restrict__ rpb,
                                             f16* __restrict__ aw, int winbase) {
    __shared__ float kls[64 * 32];
    __shared__ float vls[64 * 32];
    __shared__ float pls[64 * 64];
    __shared__ float rl[225];
    __shared__ int vreg[64];
    const int wl = blockIdx.x >> 3, h = blockIdx.x & 7;
    const int lane = threadIdx.x;
    const size_t base = ((size_t)wl * 8 + h) * 2048;

    {   // stage K,V row `lane` (32 f16 = 4x uint4), unpack to f32
        const uint4* ks = (const uint4*)(kk + base + lane * 32);
        const uint4* vs = (const uint4*)(vv + base + lane * 32);
#pragma unroll
        for (int c = 0; c < 4; c++) {
            uint4 u = ks[c]; const f16* hp = (const f16*)&u;
#pragma unroll
            for (int e = 0; e < 8; e++) kls[lane * 32 + c * 8 + e] = (float)hp[e];
            uint4 u2 = vs[c]; const f16* hp2 = (const f16*)&u2;
#pragma unroll
            for (int e = 0; e < 8; e++) vls[lane * 32 + c * 8 + e] = (float)hp2[e];
        }
    }
    float qr[32];
    {
        const uint4* qs = (const uint4*)(q + base + lane * 32);
#pragma unroll
        for (int c = 0; c < 4; c++) {
            uint4 u = qs[c]; const f16* hp = (const f16*)&u;
#pragma unroll
            for (int e = 0; e < 8; e++) qr[c * 8 + e] = (float)hp[e];
        }
    }
    for (int i = lane; i < 225; i += 64) rl[i] = rpb[i * 8 + h];
    {   // shift-mask region id of token `lane` for this window
        int gwin = (winbase + wl) & 63;
        int wh = gwin >> 3, ww = gwin & 7;
        int y = lane >> 3, xx = lane & 7;
        int r = (wh < 7) ? 0 : ((y < 4) ? 1 : 2);
        int c = (ww < 7) ? 0 : ((xx < 4) ? 1 : 2);
        vreg[lane] = r * 3 + c;
    }
    __syncthreads();

    const int yi = lane >> 3, xi = lane & 7;
    const int myreg = vreg[lane];
    float mx = -1e30f;
    for (int j = 0; j < 64; j++) {
        const float* kr = &kls[j * 32];
        float a0 = 0.f, a1 = 0.f, a2 = 0.f, a3 = 0.f;
#pragma unroll
        for (int c = 0; c < 32; c += 4) {
            a0 += qr[c] * kr[c];     a1 += qr[c + 1] * kr[c + 1];
            a2 += qr[c + 2] * kr[c + 2]; a3 += qr[c + 3] * kr[c + 3];
        }
        float sc = (a0 + a1) + (a2 + a3);
        int yj = j >> 3, xj = j & 7;
        sc += rl[(yi - yj + 7) * 15 + (xi - xj + 7)];
        if (myreg != vreg[j]) sc -= 100.f;
        pls[j * 64 + lane] = sc;
        mx = fmaxf(mx, sc);
    }
    float sum = 0.f;
    for (int j = 0; j < 64; j++) {
        float e = __expf(pls[j * 64 + lane] - mx);
        pls[j * 64 + lane] = e;
        sum += e;
    }
    float inv = 1.f / sum;
    float o[32];
#pragma unroll
    for (int c = 0; c < 32; c++) o[c] = 0.f;
    for (int j = 0; j < 64; j++) {
        float p = pls[j * 64 + lane];
        const float4* vr = (const float4*)&vls[j * 32];
#pragma unroll
        for (int c = 0; c < 8; c++) {
            float4 v4 = vr[c];
            o[c*4+0] += p * v4.x; o[c*4+1] += p * v4.y;
            o[c*4+2] += p * v4.z; o[c*4+3] += p * v4.w;
        }
    }
    f16 ob[32];
#pragma unroll
    for (int c = 0; c < 32; c++) ob[c] = (f16)(o[c] * inv);
    uint4* dst = (uint4*)(aw + ((size_t)(wl * 64 + lane)) * CC + h * 32);
    const uint4* sp = (const uint4*)ob;
#pragma unroll
    for (int c = 0; c < 4; c++) dst[c] = sp[c];
}

extern "C" void kernel_launch(void* const* d_in, const int* in_sizes, int n_in,
                              void* d_out, int out_size, void* d_ws, size_t ws_size,
                              hipStream_t stream) {
    (void)in_sizes; (void)n_in; (void)out_size; (void)ws_size;
    const float* x      = (const float*)d_in[0];
    const float* g1     = (const float*)d_in[1];
    const float* b1     = (const float*)d_in[2];
    const float* qkv_w  = (const float*)d_in[3];
    const float* qkv_b  = (const float*)d_in[4];
    const float* rpb    = (const float*)d_in[5];
    const float* proj_w = (const float*)d_in[6];
    const float* proj_b = (const float*)d_in[7];
    const float* g2     = (const float*)d_in[8];
    const float* b2     = (const float*)d_in[9];
    const float* fc1_w  = (const float*)d_in[10];
    const float* fc1_b  = (const float*)d_in[11];
    const float* fc2_w  = (const float*)d_in[12];
    const float* fc2_b  = (const float*)d_in[13];
    float* out = (float*)d_out;
    char* ws = (char*)d_ws;
    f16* wq   = (f16*)(ws + OFF_WQ);
    f16* wp   = (f16*)(ws + OFF_WP);
    f16* w1   = (f16*)(ws + OFF_W1);
    f16* w2   = (f16*)(ws + OFF_W2);
    f16* hwin = (f16*)(ws + OFF_HWIN);
    f16* m_in = hwin;                       // alias: hwin dead after QKV GEMMs
    f16* qb   = (f16*)(ws + OFF_Q);
    f16* kb   = (f16*)(ws + OFF_K);
    f16* vb   = (f16*)(ws + OFF_V);
    f16* awb  = (f16*)(ws + OFF_AW);
    f16* mh   = (f16*)(ws + OFF_MH);

    k_cvt<<<768, 256, 0, stream>>>(qkv_w, wq, 768 * 256);
    k_cvt<<<256, 256, 0, stream>>>(proj_w, wp, 256 * 256);
    k_cvt<<<1024, 256, 0, stream>>>(fc1_w, w1, 1024 * 256);
    k_cvt<<<1024, 256, 0, stream>>>(fc2_w, w2, 1024 * 256);

    k_ln<true><<<ROWS / 4, 256, 0, stream>>>(x, g1, b1, hwin);

    for (int c = 0; c < CHUNKS; c++) {
        k_gemm<256, 0><<<dim3(CROWS / 128, 6), 256, 0, stream>>>(
            hwin + (size_t)c * CROWS * CC, wq, qkv_b, c * CROWS,
            nullptr, nullptr, nullptr, qb, kb, vb);
        k_attn<<<CWINS * 8, 64, 0, stream>>>(qb, kb, vb, rpb, awb, c * CWINS);
        k_gemm<256, 1><<<dim3(CROWS / 128, 2), 256, 0, stream>>>(
            awb, wp, proj_b, c * CROWS,
            x, out, nullptr, nullptr, nullptr, nullptr);
    }

    k_ln<false><<<ROWS / 4, 256, 0, stream>>>(out, g2, b2, m_in);

    for (int c = 0; c < CHUNKS; c++) {
        k_gemm<256, 2><<<dim3(CROWS / 128, 8), 256, 0, stream>>>(
            m_in + (size_t)c * CROWS * CC, w1, fc1_b, c * CROWS,
            nullptr, nullptr, mh, nullptr, nullptr, nullptr);
        k_gemm<1024, 3><<<dim3(CROWS / 128, 2), 256, 0, stream>>>(
            mh, w2, fc2_b, c * CROWS,
            nullptr, out, nullptr, nullptr, nullptr, nullptr);
    }
}

// Round 2
// 984.907 us; speedup vs baseline: 1.3423x; 1.3423x over previous
//
#include <hip/hip_runtime.h>
#include <hip/hip_bf16.h>
#include <stdint.h>

using f16 = _Float16;
typedef _Float16 f16x8 __attribute__((ext_vector_type(8)));
typedef float f32x4 __attribute__((ext_vector_type(4)));

static constexpr int HW = 4096;        // H*W
static constexpr int CC = 256;         // channels
static constexpr int ROWS = 131072;    // B*H*W
static constexpr int ACH = 4;          // attention-phase chunks
static constexpr int AROWS = ROWS / ACH;      // 32768 rows / chunk
static constexpr int CWINS = AROWS / 64;      // 512 windows / chunk
static constexpr int MCH = 4;          // MLP-phase chunks
static constexpr int MROWS = ROWS / MCH;      // 32768 rows / chunk
static constexpr int SSH = 4;          // shift

// workspace layout (bytes) — total 135,790,592 (identical to proven round-1 footprint)
static constexpr size_t OFF_WQ = 0;                               // qkv_w f16  768*256
static constexpr size_t OFF_WP = OFF_WQ + (size_t)768*256*2;      // proj_w f16 256*256
static constexpr size_t OFF_W1 = OFF_WP + (size_t)256*256*2;      // fc1_w f16  1024*256
static constexpr size_t OFF_W2 = OFF_W1 + (size_t)1024*256*2;     // fc2_w f16  256*1024
static constexpr size_t OFF_R1 = OFF_W2 + (size_t)256*1024*2;     // 67,108,864 B region
static constexpr size_t OFF_R2 = OFF_R1 + (size_t)ROWS*CC*2;      // 67,108,864 B region
// R1: attention phase = AW full (131072x256 f16); MLP phase = MH chunk (32768x1024 f16)
// R2: attention phase = hwin chunk + Q + K + V (4 x 16,777,216 B); MLP phase = m_in full

__device__ __forceinline__ void gload16(void* lds, const void* g) {
    __builtin_amdgcn_global_load_lds(
        (const __attribute__((address_space(1))) unsigned int*)g,
        (__attribute__((address_space(3))) unsigned int*)lds, 16, 0, 0);
}

__global__ void k_cvt(const float* __restrict__ s, f16* __restrict__ d, int n) {
    int i = blockIdx.x * 256 + threadIdx.x;
    if (i < n) d[i] = (f16)s[i];
}

// LayerNorm over C=256. WIN=true: dest row (windowed, rolled, global index grow)
// gathers from source row of x. dst is chunk-local (row lrow), src mapping uses grow.
template<bool WIN>
__global__ __launch_bounds__(256) void k_ln(const float* __restrict__ x,
                                            const float* __restrict__ g,
                                            const float* __restrict__ be,
                                            f16* __restrict__ dst, int rowbase) {
    int lrow = blockIdx.x * 4 + (threadIdx.x >> 6);
    int grow = rowbase + lrow;
    int lane = threadIdx.x & 63;
    size_t srow;
    if constexpr (WIN) {
        int n = grow & 63, win = (grow >> 6) & 63, b = grow >> 12;
        int hh  = ((win >> 3) << 3) | (n >> 3);
        int wwc = ((win & 7) << 3) | (n & 7);
        int ho = (hh + SSH) & 63, wo = (wwc + SSH) & 63;   // rolled[hh] = x[(hh+SS)%64]
        srow = (size_t)b * HW + ho * 64 + wo;
    } else {
        srow = (size_t)grow;
    }
    float4 v = ((const float4*)(x + srow * CC))[lane];
    float s  = v.x + v.y + v.z + v.w;
    float s2 = v.x*v.x + v.y*v.y + v.z*v.z + v.w*v.w;
#pragma unroll
    for (int off = 32; off; off >>= 1) { s += __shfl_xor(s, off); s2 += __shfl_xor(s2, off); }
    float mean = s * (1.f/256.f);
    float rstd = rsqrtf(s2 * (1.f/256.f) - mean*mean + 1e-5f);
    float4 gv = ((const float4*)g)[lane];
    float4 bv = ((const float4*)be)[lane];
    f16 ob[4];
    ob[0] = (f16)((v.x-mean)*rstd*gv.x + bv.x);
    ob[1] = (f16)((v.y-mean)*rstd*gv.y + bv.y);
    ob[2] = (f16)((v.z-mean)*rstd*gv.z + bv.z);
    ob[3] = (f16)((v.w-mean)*rstd*gv.w + bv.w);
    *(uint2*)(dst + (size_t)lrow * CC + lane * 4) = *(const uint2*)ob;
}

// GEMM: out[M x N] = A[M x K] * Wt[N x K]^T (+bias, epilogue EPI).
// 256 thr = 4 waves (2x2 of 64x64), tile 128x128, BK=32, mfma 16x16x32 f16.
// Staging via global_load_lds width=16 (m97 pattern): LDS dest wave-uniform base,
// per-lane global source; [128][32] f16 linear layout (per-wave frag reads are
// contiguous 1KB -> conflict-free).
// EPI: 0=qkv split(q-scaled), 1=proj+unshift+residual->outf, 2=fc1+gelu->outh,
//      3=fc2+residual(outf in-place)
template<int KDIM, int EPI>
__global__ __launch_bounds__(256) void k_gemm(const f16* __restrict__ A,
                                              const f16* __restrict__ Wt,
                                              const float* __restrict__ bias,
                                              int rowbase,
                                              const float* __restrict__ x_in,
                                              float* outf, f16* __restrict__ outh,
                                              f16* __restrict__ q, f16* __restrict__ kk,
                                              f16* __restrict__ vv) {
    __shared__ f16 As[128 * 32];
    __shared__ f16 Bs[128 * 32];
    const int tid = threadIdx.x;
    const int m0 = blockIdx.x * 128, n0 = blockIdx.y * 128;
    const int wave = tid >> 6, lane = tid & 63;
    const int wm = (wave >> 1) * 64, wn = (wave & 1) * 64;
    const int lr = lane & 15, kq = lane >> 4;
    // staging addresses for this thread: chunk idx = (wave*2+t)*64+lane
    const int i0 = wave * 128 + lane;          // t=0 chunk index
    const int r0 = i0 >> 2, c0 = (i0 & 3) * 8;
    const int i1 = i0 + 64;                    // t=1 chunk index
    const int r1 = i1 >> 2, c1 = (i1 & 3) * 8;
    f32x4 acc[4][4];
#pragma unroll
    for (int i = 0; i < 4; i++)
#pragma unroll
        for (int j = 0; j < 4; j++) acc[i][j] = f32x4{0.f, 0.f, 0.f, 0.f};

    for (int k0 = 0; k0 < KDIM; k0 += 32) {
        gload16(&As[(size_t)i0 * 8 - lane * 8], &A [(size_t)(m0 + r0) * KDIM + k0 + c0]);
        gload16(&Bs[(size_t)i0 * 8 - lane * 8], &Wt[(size_t)(n0 + r0) * KDIM + k0 + c0]);
        gload16(&As[(size_t)i1 * 8 - lane * 8], &A [(size_t)(m0 + r1) * KDIM + k0 + c1]);
        gload16(&Bs[(size_t)i1 * 8 - lane * 8], &Wt[(size_t)(n0 + r1) * KDIM + k0 + c1]);
        __syncthreads();
        f16x8 af[4], bfv[4];
#pragma unroll
        for (int i = 0; i < 4; i++) {
            af[i]  = *(const f16x8*)(&As[(wm + i * 16 + lr) * 32 + kq * 8]);
            bfv[i] = *(const f16x8*)(&Bs[(wn + i * 16 + lr) * 32 + kq * 8]);
        }
#pragma unroll
        for (int mi = 0; mi < 4; mi++)
#pragma unroll
            for (int ni = 0; ni < 4; ni++)
                acc[mi][ni] = __builtin_amdgcn_mfma_f32_16x16x32_f16(af[mi], bfv[ni], acc[mi][ni], 0, 0, 0);
        __syncthreads();
    }

#pragma unroll
    for (int mi = 0; mi < 4; mi++)
#pragma unroll
        for (int ni = 0; ni < 4; ni++)
#pragma unroll
            for (int j = 0; j < 4; j++) {
                int lrow = m0 + wm + mi * 16 + kq * 4 + j;   // C/D: row=(lane>>4)*4+j
                int gcol = n0 + wn + ni * 16 + lr;           //      col=lane&15
                float val = acc[mi][ni][j] + bias[gcol];
                int grow = rowbase + lrow;
                if constexpr (EPI == 0) {        // qkv: split into per-head q,k,v (chunk-local)
                    int s = gcol >> 8, h2 = (gcol >> 5) & 7, d = gcol & 31;
                    if (s == 0) val *= 0.1767766952966369f;  // HD^-0.5
                    f16* dst = (s == 0) ? q : (s == 1 ? kk : vv);
                    int winl = lrow >> 6, n = lrow & 63;
                    dst[(((size_t)winl * 8 + h2) * 64 + n) * 32 + d] = (f16)val;
                } else if constexpr (EPI == 1) { // proj + un-shift + shortcut residual -> outf
                    int n = grow & 63, win = (grow >> 6) & 63, b = grow >> 12;
                    int hh  = ((win >> 3) << 3) | (n >> 3);
                    int wwc = ((win & 7) << 3) | (n & 7);
                    int ho = (hh + SSH) & 63, wo = (wwc + SSH) & 63;
                    size_t idx = ((size_t)b * HW + ho * 64 + wo) * CC + gcol;
                    outf[idx] = x_in[idx] + val;
                } else if constexpr (EPI == 2) { // fc1 + gelu(tanh approx, JAX default)
                    float z = 0.7978845608028654f * (val + 0.044715f * val * val * val);
                    float t = 1.f - 2.f / (__expf(2.f * z) + 1.f);
                    outh[(size_t)lrow * 1024 + gcol] = (f16)(0.5f * val * (1.f + t));
                } else {                          // fc2 + residual: outf holds x2, accumulate
                    size_t idx = (size_t)grow * CC + gcol;
                    outf[idx] = outf[idx] + val;
                }
            }
}

// One wave per (window, head). Scores/P in LDS [key][query-lane]; K,V staged f32.
__global__ __launch_bounds__(64) void k_attn(const f16* __restrict__ q,
                                             const f16* __restrict__ kk,
                                             const f16* __restrict__ vv,
                                             const float* __restrict__ rpb,
                                             f16* __restrict__ aw, int winbase) {
    __shared__ float kls[64 * 32];
    __shared__ float vls[64 * 32];
    __shared__ float pls[64 * 64];
    __shared__ float rl[225];
    __shared__ int vreg[64];
    const int wl = blockIdx.x >> 3, h = blockIdx.x & 7;
    const int lane = threadIdx.x;
    const size_t base = ((size_t)wl * 8 + h) * 2048;

    {   // stage K,V row `lane` (32 f16), unpack to f32
        const uint4* ks = (const uint4*)(kk + base + lane * 32);
        const uint4* vs = (const uint4*)(vv + base + lane * 32);
#pragma unroll
        for (int c = 0; c < 4; c++) {
            uint4 u = ks[c]; const f16* hp = (const f16*)&u;
#pragma unroll
            for (int e = 0; e < 8; e++) kls[lane * 32 + c * 8 + e] = (float)hp[e];
            uint4 u2 = vs[c]; const f16* hp2 = (const f16*)&u2;
#pragma unroll
            for (int e = 0; e < 8; e++) vls[lane * 32 + c * 8 + e] = (float)hp2[e];
        }
    }
    float qr[32];
    {
        const uint4* qs = (const uint4*)(q + base + lane * 32);
#pragma unroll
        for (int c = 0; c < 4; c++) {
            uint4 u = qs[c]; const f16* hp = (const f16*)&u;
#pragma unroll
            for (int e = 0; e < 8; e++) qr[c * 8 + e] = (float)hp[e];
        }
    }
    for (int i = lane; i < 225; i += 64) rl[i] = rpb[i * 8 + h];
    {   // shift-mask region id of token `lane` for this window
        int gwin = (winbase + wl) & 63;
        int wh = gwin >> 3, ww = gwin & 7;
        int y = lane >> 3, xx = lane & 7;
        int r = (wh < 7) ? 0 : ((y < 4) ? 1 : 2);
        int c = (ww < 7) ? 0 : ((xx < 4) ? 1 : 2);
        vreg[lane] = r * 3 + c;
    }
    __syncthreads();

    const int yi = lane >> 3, xi = lane & 7;
    const int myreg = vreg[lane];
    float mx = -1e30f;
    for (int j = 0; j < 64; j++) {
        const float* kr = &kls[j * 32];
        float a0 = 0.f, a1 = 0.f, a2 = 0.f, a3 = 0.f;
#pragma unroll
        for (int c = 0; c < 32; c += 4) {
            a0 += qr[c] * kr[c];     a1 += qr[c + 1] * kr[c + 1];
            a2 += qr[c + 2] * kr[c + 2]; a3 += qr[c + 3] * kr[c + 3];
        }
        float sc = (a0 + a1) + (a2 + a3);
        int yj = j >> 3, xj = j & 7;
        sc += rl[(yi - yj + 7) * 15 + (xi - xj + 7)];
        if (myreg != vreg[j]) sc -= 100.f;
        pls[j * 64 + lane] = sc;
        mx = fmaxf(mx, sc);
    }
    float sum = 0.f;
    for (int j = 0; j < 64; j++) {
        float e = __expf(pls[j * 64 + lane] - mx);
        pls[j * 64 + lane] = e;
        sum += e;
    }
    float inv = 1.f / sum;
    float o[32];
#pragma unroll
    for (int c = 0; c < 32; c++) o[c] = 0.f;
    for (int j = 0; j < 64; j++) {
        float p = pls[j * 64 + lane];
        const float4* vr = (const float4*)&vls[j * 32];
#pragma unroll
        for (int c = 0; c < 8; c++) {
            float4 v4 = vr[c];
            o[c*4+0] += p * v4.x; o[c*4+1] += p * v4.y;
            o[c*4+2] += p * v4.z; o[c*4+3] += p * v4.w;
        }
    }
    f16 ob[32];
#pragma unroll
    for (int c = 0; c < 32; c++) ob[c] = (f16)(o[c] * inv);
    uint4* dst = (uint4*)(aw + ((size_t)(wl * 64 + lane)) * CC + h * 32);
    const uint4* sp = (const uint4*)ob;
#pragma unroll
    for (int c = 0; c < 4; c++) dst[c] = sp[c];
}

extern "C" void kernel_launch(void* const* d_in, const int* in_sizes, int n_in,
                              void* d_out, int out_size, void* d_ws, size_t ws_size,
                              hipStream_t stream) {
    (void)in_sizes; (void)n_in; (void)out_size; (void)ws_size;
    const float* x      = (const float*)d_in[0];
    const float* g1     = (const float*)d_in[1];
    const float* b1     = (const float*)d_in[2];
    const float* qkv_w  = (const float*)d_in[3];
    const float* qkv_b  = (const float*)d_in[4];
    const float* rpb    = (const float*)d_in[5];
    const float* proj_w = (const float*)d_in[6];
    const float* proj_b = (const float*)d_in[7];
    const float* g2     = (const float*)d_in[8];
    const float* b2     = (const float*)d_in[9];
    const float* fc1_w  = (const float*)d_in[10];
    const float* fc1_b  = (const float*)d_in[11];
    const float* fc2_w  = (const float*)d_in[12];
    const float* fc2_b  = (const float*)d_in[13];
    float* out = (float*)d_out;
    char* ws = (char*)d_ws;
    f16* wq = (f16*)(ws + OFF_WQ);
    f16* wp = (f16*)(ws + OFF_WP);
    f16* w1 = (f16*)(ws + OFF_W1);
    f16* w2 = (f16*)(ws + OFF_W2);
    // R1: AW full (attn out, windowed order) / MH chunk (MLP hidden)
    f16* awb = (f16*)(ws + OFF_R1);
    f16* mh  = (f16*)(ws + OFF_R1);
    // R2: hwin chunk + Q + K + V   /   m_in full
    static constexpr size_t QSZ = (size_t)CWINS * 8 * 64 * 32 * 2; // 16,777,216 B
    f16* hwin = (f16*)(ws + OFF_R2);
    f16* qb   = (f16*)(ws + OFF_R2 + QSZ);
    f16* kb   = (f16*)(ws + OFF_R2 + 2 * QSZ);
    f16* vb   = (f16*)(ws + OFF_R2 + 3 * QSZ);
    f16* m_in = (f16*)(ws + OFF_R2);

    k_cvt<<<768, 256, 0, stream>>>(qkv_w, wq, 768 * 256);
    k_cvt<<<256, 256, 0, stream>>>(proj_w, wp, 256 * 256);
    k_cvt<<<1024, 256, 0, stream>>>(fc1_w, w1, 1024 * 256);
    k_cvt<<<1024, 256, 0, stream>>>(fc2_w, w2, 1024 * 256);

    // --- attention phase: per chunk LN1 -> QKV -> attn (writes full AW) ---
    for (int c = 0; c < ACH; c++) {
        k_ln<true><<<AROWS / 4, 256, 0, stream>>>(x, g1, b1, hwin, c * AROWS);
        k_gemm<256, 0><<<dim3(AROWS / 128, 6), 256, 0, stream>>>(
            hwin, wq, qkv_b, 0, nullptr, nullptr, nullptr, qb, kb, vb);
        k_attn<<<CWINS * 8, 64, 0, stream>>>(
            qb, kb, vb, rpb, awb + (size_t)c * AROWS * CC, c * CWINS);
    }
    // proj over full M (2048 blocks), fused un-shift + residual -> out
    k_gemm<256, 1><<<dim3(ROWS / 128, 2), 256, 0, stream>>>(
        awb, wp, proj_b, 0, x, out, nullptr, nullptr, nullptr, nullptr);

    // --- MLP phase ---
    k_ln<false><<<ROWS / 4, 256, 0, stream>>>(out, g2, b2, m_in, 0);
    for (int c = 0; c < MCH; c++) {
        k_gemm<256, 2><<<dim3(MROWS / 128, 8), 256, 0, stream>>>(
            m_in + (size_t)c * MROWS * CC, w1, fc1_b, c * MROWS,
            nullptr, nullptr, mh, nullptr, nullptr, nullptr);
        k_gemm<1024, 3><<<dim3(MROWS / 128, 2), 256, 0, stream>>>(
            mh, w2, fc2_b, c * MROWS,
            nullptr, out, nullptr, nullptr, nullptr, nullptr);
    }
}

// Round 3
// 933.100 us; speedup vs baseline: 1.4169x; 1.0555x over previous
//
#include <hip/hip_runtime.h>
#include <hip/hip_bf16.h>
#include <stdint.h>

using f16 = _Float16;
typedef _Float16 f16x8 __attribute__((ext_vector_type(8)));
typedef float f32x4 __attribute__((ext_vector_type(4)));

static constexpr int HW = 4096;        // H*W
static constexpr int CC = 256;         // channels
static constexpr int ROWS = 131072;    // B*H*W
static constexpr int ACH = 4;          // attention-phase chunks
static constexpr int AROWS = ROWS / ACH;      // 32768 rows / chunk
static constexpr int CWINS = AROWS / 64;      // 512 windows / chunk
static constexpr int MCH = 4;          // MLP-phase chunks
static constexpr int MROWS = ROWS / MCH;      // 32768 rows / chunk
static constexpr int SSH = 4;          // shift

// workspace layout (bytes) — total 135,790,592 (proven footprint)
static constexpr size_t OFF_WQ = 0;                               // qkv_w f16  768*256
static constexpr size_t OFF_WP = OFF_WQ + (size_t)768*256*2;      // proj_w f16 256*256
static constexpr size_t OFF_W1 = OFF_WP + (size_t)256*256*2;      // fc1_w f16  1024*256
static constexpr size_t OFF_W2 = OFF_W1 + (size_t)1024*256*2;     // fc2_w f16  256*1024
static constexpr size_t OFF_R1 = OFF_W2 + (size_t)256*1024*2;     // 67,108,864 B region
static constexpr size_t OFF_R2 = OFF_R1 + (size_t)ROWS*CC*2;      // 67,108,864 B region
// R1: attn phase = AW full (131072x256 f16); MLP phase = MH chunk (32768x1024 f16)
// R2: attn phase = hwin chunk + Q + K + V (4 x 16.78 MB); then m_in full (written by k_proj)

__device__ __forceinline__ void gload16(void* lds, const void* g) {
    __builtin_amdgcn_global_load_lds(
        (const __attribute__((address_space(1))) unsigned int*)g,
        (__attribute__((address_space(3))) unsigned int*)lds, 16, 0, 0);
}

__global__ void k_cvt(const float* __restrict__ s, f16* __restrict__ d, int n) {
    int i = blockIdx.x * 256 + threadIdx.x;
    if (i < n) d[i] = (f16)s[i];
}

// LayerNorm over C=256, dest row (windowed+rolled) gathers from source row of x.
__global__ __launch_bounds__(256) void k_ln(const float* __restrict__ x,
                                            const float* __restrict__ g,
                                            const float* __restrict__ be,
                                            f16* __restrict__ dst, int rowbase) {
    int lrow = blockIdx.x * 4 + (threadIdx.x >> 6);
    int grow = rowbase + lrow;
    int lane = threadIdx.x & 63;
    int n = grow & 63, win = (grow >> 6) & 63, b = grow >> 12;
    int hh  = ((win >> 3) << 3) | (n >> 3);
    int wwc = ((win & 7) << 3) | (n & 7);
    int ho = (hh + SSH) & 63, wo = (wwc + SSH) & 63;   // rolled[hh] = x[(hh+SS)%64]
    size_t srow = (size_t)b * HW + ho * 64 + wo;
    float4 v = ((const float4*)(x + srow * CC))[lane];
    float s  = v.x + v.y + v.z + v.w;
    float s2 = v.x*v.x + v.y*v.y + v.z*v.z + v.w*v.w;
#pragma unroll
    for (int off = 32; off; off >>= 1) { s += __shfl_xor(s, off); s2 += __shfl_xor(s2, off); }
    float mean = s * (1.f/256.f);
    float rstd = rsqrtf(s2 * (1.f/256.f) - mean*mean + 1e-5f);
    float4 gv = ((const float4*)g)[lane];
    float4 bv = ((const float4*)be)[lane];
    f16 ob[4];
    ob[0] = (f16)((v.x-mean)*rstd*gv.x + bv.x);
    ob[1] = (f16)((v.y-mean)*rstd*gv.y + bv.y);
    ob[2] = (f16)((v.z-mean)*rstd*gv.z + bv.z);
    ob[3] = (f16)((v.w-mean)*rstd*gv.w + bv.w);
    *(uint2*)(dst + (size_t)lrow * CC + lane * 4) = *(const uint2*)ob;
}

// GEMM: out[M x N] = A[M x K] * Wt[N x K]^T (+bias, epilogue EPI).
// 256 thr = 4 waves (2x2 of 64x64), tile 128x128, BK=32, mfma 16x16x32 f16.
// 2-phase double-buffered staging: issue next tile's global_load_lds BEFORE
// computing current (latency hides under ds_read+MFMA; barrier drains after).
// EPI: 0=qkv split(q-scaled), 2=fc1+gelu->outh, 3=fc2+residual(outf in-place)
template<int KDIM, int EPI>
__global__ __launch_bounds__(256) void k_gemm(const f16* __restrict__ A,
                                              const f16* __restrict__ Wt,
                                              const float* __restrict__ bias,
                                              int rowbase,
                                              float* outf, f16* __restrict__ outh,
                                              f16* __restrict__ q, f16* __restrict__ kk,
                                              f16* __restrict__ vv) {
    __shared__ f16 As[2][128 * 32];
    __shared__ f16 Bs[2][128 * 32];
    const int tid = threadIdx.x;
    const int m0 = blockIdx.x * 128, n0 = blockIdx.y * 128;
    const int wave = tid >> 6, lane = tid & 63;
    const int wm = (wave >> 1) * 64, wn = (wave & 1) * 64;
    const int lr = lane & 15, kq = lane >> 4;
    const int i0 = wave * 128 + lane;          // t=0 chunk index
    const int r0 = i0 >> 2, c0 = (i0 & 3) * 8;
    const int i1 = i0 + 64;                    // t=1 chunk index
    const int r1 = i1 >> 2, c1 = (i1 & 3) * 8;
    const int base0 = wave * 1024;             // f16 idx of wave's chunk base (t=0)
    const int base1 = base0 + 512;

    auto stage = [&](int b, int k0) {
        gload16(&As[b][base0], &A [(size_t)(m0 + r0) * KDIM + k0 + c0]);
        gload16(&Bs[b][base0], &Wt[(size_t)(n0 + r0) * KDIM + k0 + c0]);
        gload16(&As[b][base1], &A [(size_t)(m0 + r1) * KDIM + k0 + c1]);
        gload16(&Bs[b][base1], &Wt[(size_t)(n0 + r1) * KDIM + k0 + c1]);
    };

    f32x4 acc[4][4];
#pragma unroll
    for (int i = 0; i < 4; i++)
#pragma unroll
        for (int j = 0; j < 4; j++) acc[i][j] = f32x4{0.f, 0.f, 0.f, 0.f};

    constexpr int KSTEPS = KDIM / 32;
    stage(0, 0);
    __syncthreads();
    for (int s = 0; s < KSTEPS; s++) {
        int cur = s & 1;
        if (s + 1 < KSTEPS) stage(cur ^ 1, (s + 1) * 32);
        f16x8 af[4], bfv[4];
#pragma unroll
        for (int i = 0; i < 4; i++) {
            af[i]  = *(const f16x8*)(&As[cur][(wm + i * 16 + lr) * 32 + kq * 8]);
            bfv[i] = *(const f16x8*)(&Bs[cur][(wn + i * 16 + lr) * 32 + kq * 8]);
        }
#pragma unroll
        for (int mi = 0; mi < 4; mi++)
#pragma unroll
            for (int ni = 0; ni < 4; ni++)
                acc[mi][ni] = __builtin_amdgcn_mfma_f32_16x16x32_f16(af[mi], bfv[ni], acc[mi][ni], 0, 0, 0);
        __syncthreads();   // drains vmcnt(0): next-stage loads waited AFTER compute
    }

#pragma unroll
    for (int mi = 0; mi < 4; mi++)
#pragma unroll
        for (int ni = 0; ni < 4; ni++)
#pragma unroll
            for (int j = 0; j < 4; j++) {
                int lrow = m0 + wm + mi * 16 + kq * 4 + j;   // C/D: row=(lane>>4)*4+j
                int gcol = n0 + wn + ni * 16 + lr;           //      col=lane&15
                float val = acc[mi][ni][j] + bias[gcol];
                int grow = rowbase + lrow;
                if constexpr (EPI == 0) {        // qkv: split into per-head q,k,v (chunk-local)
                    int s = gcol >> 8, h2 = (gcol >> 5) & 7, d = gcol & 31;
                    if (s == 0) val *= 0.1767766952966369f;  // HD^-0.5
                    f16* dst = (s == 0) ? q : (s == 1 ? kk : vv);
                    int winl = lrow >> 6, n = lrow & 63;
                    dst[(((size_t)winl * 8 + h2) * 64 + n) * 32 + d] = (f16)val;
                } else if constexpr (EPI == 2) { // fc1 + gelu (tanh approx, JAX default)
                    float z = 0.7978845608028654f * (val + 0.044715f * val * val * val);
                    float t = 1.f - 2.f / (__expf(2.f * z) + 1.f);
                    outh[(size_t)lrow * 1024 + gcol] = (f16)(0.5f * val * (1.f + t));
                } else {                          // fc2 + residual: outf holds x2, accumulate
                    size_t idx = (size_t)grow * CC + gcol;
                    outf[idx] = outf[idx] + val;
                }
            }
}

// proj GEMM, tile 64 rows x 256 cols (full row per block), 4 waves (1x4 of 64x64).
// Epilogue: + proj bias, + un-shift scatter + shortcut residual -> d_out (f32),
// then in-block LayerNorm2 over the complete 256-wide row -> m_in (f16).
__global__ __launch_bounds__(256, 2) void k_proj(const f16* __restrict__ A,
                                                 const f16* __restrict__ Wt,
                                                 const float* __restrict__ bias,
                                                 const float* __restrict__ x_in,
                                                 float* __restrict__ outf,
                                                 f16* __restrict__ m_out,
                                                 const float* __restrict__ g2,
                                                 const float* __restrict__ b2) {
    __shared__ f16 As[2][64 * 32];
    __shared__ f16 Bs[2][256 * 32];
    __shared__ float rsum[4][64];
    __shared__ float rsq[4][64];
    const int tid = threadIdx.x;
    const int m0 = blockIdx.x * 64;
    const int wave = tid >> 6, lane = tid & 63;
    const int lr = lane & 15, kq = lane >> 4;
    const int ar = tid >> 2, ac = (tid & 3) * 8;   // A stage: 256 chunks, 1/thread

    auto stage = [&](int b, int k0) {
        gload16(&As[b][wave * 512], &A[(size_t)(m0 + ar) * CC + k0 + ac]);
#pragma unroll
        for (int r = 0; r < 4; r++)
            gload16(&Bs[b][(r * 256 + wave * 64) * 8],
                    &Wt[(size_t)(r * 64 + ar) * CC + k0 + ac]);
    };

    f32x4 acc[4][4];
#pragma unroll
    for (int i = 0; i < 4; i++)
#pragma unroll
        for (int j = 0; j < 4; j++) acc[i][j] = f32x4{0.f, 0.f, 0.f, 0.f};

    stage(0, 0);
    __syncthreads();
    for (int s = 0; s < 8; s++) {
        int cur = s & 1;
        if (s + 1 < 8) stage(cur ^ 1, (s + 1) * 32);
        f16x8 af[4], bfv[4];
#pragma unroll
        for (int i = 0; i < 4; i++) {
            af[i]  = *(const f16x8*)(&As[cur][(i * 16 + lr) * 32 + kq * 8]);
            bfv[i] = *(const f16x8*)(&Bs[cur][(wave * 64 + i * 16 + lr) * 32 + kq * 8]);
        }
#pragma unroll
        for (int mi = 0; mi < 4; mi++)
#pragma unroll
            for (int ni = 0; ni < 4; ni++)
                acc[mi][ni] = __builtin_amdgcn_mfma_f32_16x16x32_f16(af[mi], bfv[ni], acc[mi][ni], 0, 0, 0);
        __syncthreads();
    }

    // ---- epilogue: x2 = proj + bias + shortcut (per un-shift scatter) ----
    int srows[4][4];
#pragma unroll
    for (int mi = 0; mi < 4; mi++)
#pragma unroll
        for (int j = 0; j < 4; j++) {
            int row = m0 + mi * 16 + kq * 4 + j;       // windowed-order global row
            int n = row & 63, win = (row >> 6) & 63, b = row >> 12;
            int hh  = ((win >> 3) << 3) | (n >> 3);
            int wwc = ((win & 7) << 3) | (n & 7);
            int ho = (hh + SSH) & 63, wo = (wwc + SSH) & 63;
            srows[mi][j] = b * HW + ho * 64 + wo;
        }
    float bv[4], gv[4], b2v[4];
#pragma unroll
    for (int ni = 0; ni < 4; ni++) {
        int gcol = wave * 64 + ni * 16 + lr;
        bv[ni] = bias[gcol]; gv[ni] = g2[gcol]; b2v[ni] = b2[gcol];
    }
    float ps[4][4], qs[4][4];
#pragma unroll
    for (int mi = 0; mi < 4; mi++)
#pragma unroll
        for (int j = 0; j < 4; j++) { ps[mi][j] = 0.f; qs[mi][j] = 0.f; }
#pragma unroll
    for (int mi = 0; mi < 4; mi++)
#pragma unroll
        for (int ni = 0; ni < 4; ni++) {
            int gcol = wave * 64 + ni * 16 + lr;
#pragma unroll
            for (int j = 0; j < 4; j++) {
                size_t idx = (size_t)srows[mi][j] * CC + gcol;
                float v = acc[mi][ni][j] + bv[ni] + x_in[idx];
                acc[mi][ni][j] = v;
                outf[idx] = v;
                ps[mi][j] += v; qs[mi][j] += v * v;
            }
        }
    // reduce across the 16-lane lr group (covers this wave's 64 cols)
#pragma unroll
    for (int off = 1; off < 16; off <<= 1)
#pragma unroll
        for (int mi = 0; mi < 4; mi++)
#pragma unroll
            for (int j = 0; j < 4; j++) {
                ps[mi][j] += __shfl_xor(ps[mi][j], off);
                qs[mi][j] += __shfl_xor(qs[mi][j], off);
            }
    if (lr == 0) {
#pragma unroll
        for (int mi = 0; mi < 4; mi++)
#pragma unroll
            for (int j = 0; j < 4; j++) {
                int rl = mi * 16 + kq * 4 + j;
                rsum[wave][rl] = ps[mi][j];
                rsq[wave][rl]  = qs[mi][j];
            }
    }
    __syncthreads();
    float mean_a[4][4], rstd_a[4][4];
#pragma unroll
    for (int mi = 0; mi < 4; mi++)
#pragma unroll
        for (int j = 0; j < 4; j++) {
            int rl = mi * 16 + kq * 4 + j;
            float s  = rsum[0][rl] + rsum[1][rl] + rsum[2][rl] + rsum[3][rl];
            float s2 = rsq[0][rl] + rsq[1][rl] + rsq[2][rl] + rsq[3][rl];
            float mean = s * (1.f/256.f);
            float var  = s2 * (1.f/256.f) - mean * mean;
            mean_a[mi][j] = mean;
            rstd_a[mi][j] = rsqrtf(var + 1e-5f);
        }
#pragma unroll
    for (int mi = 0; mi < 4; mi++)
#pragma unroll
        for (int ni = 0; ni < 4; ni++) {
            int gcol = wave * 64 + ni * 16 + lr;
#pragma unroll
            for (int j = 0; j < 4; j++) {
                float m = (acc[mi][ni][j] - mean_a[mi][j]) * rstd_a[mi][j] * gv[ni] + b2v[ni];
                m_out[(size_t)srows[mi][j] * CC + gcol] = (f16)m;
            }
        }
}

// One wave per (window, head). Scores/P in LDS [key][query-lane]; K,V staged f32.
__global__ __launch_bounds__(64) void k_attn(const f16* __restrict__ q,
                                             const f16* __restrict__ kk,
                                             const f16* __restrict__ vv,
                                             const float* __restrict__ rpb,
                                             f16* __restrict__ aw, int winbase) {
    __shared__ float kls[64 * 32];
    __shared__ float vls[64 * 32];
    __shared__ float pls[64 * 64];
    __shared__ float rl[225];
    __shared__ int vreg[64];
    const int wl = blockIdx.x >> 3, h = blockIdx.x & 7;
    const int lane = threadIdx.x;
    const size_t base = ((size_t)wl * 8 + h) * 2048;

    {   // stage K,V row `lane` (32 f16), unpack to f32
        const uint4* ks = (const uint4*)(kk + base + lane * 32);
        const uint4* vs = (const uint4*)(vv + base + lane * 32);
#pragma unroll
        for (int c = 0; c < 4; c++) {
            uint4 u = ks[c]; const f16* hp = (const f16*)&u;
#pragma unroll
            for (int e = 0; e < 8; e++) kls[lane * 32 + c * 8 + e] = (float)hp[e];
            uint4 u2 = vs[c]; const f16* hp2 = (const f16*)&u2;
#pragma unroll
            for (int e = 0; e < 8; e++) vls[lane * 32 + c * 8 + e] = (float)hp2[e];
        }
    }
    float qr[32];
    {
        const uint4* qs = (const uint4*)(q + base + lane * 32);
#pragma unroll
        for (int c = 0; c < 4; c++) {
            uint4 u = qs[c]; const f16* hp = (const f16*)&u;
#pragma unroll
            for (int e = 0; e < 8; e++) qr[c * 8 + e] = (float)hp[e];
        }
    }
    for (int i = lane; i < 225; i += 64) rl[i] = rpb[i * 8 + h];
    {   // shift-mask region id of token `lane` for this window
        int gwin = (winbase + wl) & 63;
        int wh = gwin >> 3, ww = gwin & 7;
        int y = lane >> 3, xx = lane & 7;
        int r = (wh < 7) ? 0 : ((y < 4) ? 1 : 2);
        int c = (ww < 7) ? 0 : ((xx < 4) ? 1 : 2);
        vreg[lane] = r * 3 + c;
    }
    __syncthreads();

    const int yi = lane >> 3, xi = lane & 7;
    const int myreg = vreg[lane];
    float mx = -1e30f;
    for (int j = 0; j < 64; j++) {
        const float* kr = &kls[j * 32];
        float a0 = 0.f, a1 = 0.f, a2 = 0.f, a3 = 0.f;
#pragma unroll
        for (int c = 0; c < 32; c += 4) {
            a0 += qr[c] * kr[c];     a1 += qr[c + 1] * kr[c + 1];
            a2 += qr[c + 2] * kr[c + 2]; a3 += qr[c + 3] * kr[c + 3];
        }
        float sc = (a0 + a1) + (a2 + a3);
        int yj = j >> 3, xj = j & 7;
        sc += rl[(yi - yj + 7) * 15 + (xi - xj + 7)];
        if (myreg != vreg[j]) sc -= 100.f;
        pls[j * 64 + lane] = sc;
        mx = fmaxf(mx, sc);
    }
    float sum = 0.f;
    for (int j = 0; j < 64; j++) {
        float e = __expf(pls[j * 64 + lane] - mx);
        pls[j * 64 + lane] = e;
        sum += e;
    }
    float inv = 1.f / sum;
    float o[32];
#pragma unroll
    for (int c = 0; c < 32; c++) o[c] = 0.f;
    for (int j = 0; j < 64; j++) {
        float p = pls[j * 64 + lane];
        const float4* vr = (const float4*)&vls[j * 32];
#pragma unroll
        for (int c = 0; c < 8; c++) {
            float4 v4 = vr[c];
            o[c*4+0] += p * v4.x; o[c*4+1] += p * v4.y;
            o[c*4+2] += p * v4.z; o[c*4+3] += p * v4.w;
        }
    }
    f16 ob[32];
#pragma unroll
    for (int c = 0; c < 32; c++) ob[c] = (f16)(o[c] * inv);
    uint4* dst = (uint4*)(aw + ((size_t)(wl * 64 + lane)) * CC + h * 32);
    const uint4* sp = (const uint4*)ob;
#pragma unroll
    for (int c = 0; c < 4; c++) dst[c] = sp[c];
}

extern "C" void kernel_launch(void* const* d_in, const int* in_sizes, int n_in,
                              void* d_out, int out_size, void* d_ws, size_t ws_size,
                              hipStream_t stream) {
    (void)in_sizes; (void)n_in; (void)out_size; (void)ws_size;
    const float* x      = (const float*)d_in[0];
    const float* g1     = (const float*)d_in[1];
    const float* b1     = (const float*)d_in[2];
    const float* qkv_w  = (const float*)d_in[3];
    const float* qkv_b  = (const float*)d_in[4];
    const float* rpb    = (const float*)d_in[5];
    const float* proj_w = (const float*)d_in[6];
    const float* proj_b = (const float*)d_in[7];
    const float* g2     = (const float*)d_in[8];
    const float* b2     = (const float*)d_in[9];
    const float* fc1_w  = (const float*)d_in[10];
    const float* fc1_b  = (const float*)d_in[11];
    const float* fc2_w  = (const float*)d_in[12];
    const float* fc2_b  = (const float*)d_in[13];
    float* out = (float*)d_out;
    char* ws = (char*)d_ws;
    f16* wq = (f16*)(ws + OFF_WQ);
    f16* wp = (f16*)(ws + OFF_WP);
    f16* w1 = (f16*)(ws + OFF_W1);
    f16* w2 = (f16*)(ws + OFF_W2);
    // R1: AW full (attn out, windowed order) -> later MH chunk (MLP hidden)
    f16* awb = (f16*)(ws + OFF_R1);
    f16* mh  = (f16*)(ws + OFF_R1);
    // R2: hwin chunk + Q + K + V   ->  later m_in full (LN2 out, spatial order)
    static constexpr size_t QSZ = (size_t)CWINS * 8 * 64 * 32 * 2; // 16,777,216 B
    f16* hwin = (f16*)(ws + OFF_R2);
    f16* qb   = (f16*)(ws + OFF_R2 + QSZ);
    f16* kb   = (f16*)(ws + OFF_R2 + 2 * QSZ);
    f16* vb   = (f16*)(ws + OFF_R2 + 3 * QSZ);
    f16* m_in = (f16*)(ws + OFF_R2);

    k_cvt<<<768, 256, 0, stream>>>(qkv_w, wq, 768 * 256);
    k_cvt<<<256, 256, 0, stream>>>(proj_w, wp, 256 * 256);
    k_cvt<<<1024, 256, 0, stream>>>(fc1_w, w1, 1024 * 256);
    k_cvt<<<1024, 256, 0, stream>>>(fc2_w, w2, 1024 * 256);

    // --- attention phase: per chunk LN1 -> QKV -> attn (writes full AW) ---
    for (int c = 0; c < ACH; c++) {
        k_ln<<<AROWS / 4, 256, 0, stream>>>(x, g1, b1, hwin, c * AROWS);
        k_gemm<256, 0><<<dim3(AROWS / 128, 6), 256, 0, stream>>>(
            hwin, wq, qkv_b, 0, nullptr, nullptr, qb, kb, vb);
        k_attn<<<CWINS * 8, 64, 0, stream>>>(
            qb, kb, vb, rpb, awb + (size_t)c * AROWS * CC, c * CWINS);
    }
    // proj over full M (2048 blocks of 64 rows), fused un-shift + residual -> out,
    // fused LN2 -> m_in
    k_proj<<<ROWS / 64, 256, 0, stream>>>(awb, wp, proj_b, x, out, m_in, g2, b2);

    // --- MLP phase ---
    for (int c = 0; c < MCH; c++) {
        k_gemm<256, 2><<<dim3(MROWS / 128, 8), 256, 0, stream>>>(
            m_in + (size_t)c * MROWS * CC, w1, fc1_b, c * MROWS,
            nullptr, mh, nullptr, nullptr, nullptr);
        k_gemm<1024, 3><<<dim3(MROWS / 128, 2), 256, 0, stream>>>(
            mh, w2, fc2_b, c * MROWS,
            out, nullptr, nullptr, nullptr, nullptr);
    }
}